// Round 4
// baseline (1354.756 us; speedup 1.0000x reference)
//
#include <hip/hip_runtime.h>

// z: [32, 256, 32, 32] f32 -> zf: [N=32768, D=256];  emb_w: [K=1024, D=256] f32
// out: z_q (8388608 f32, BCHW) | loss (1 f32) | codes (131072 f32, BHW x DEPTH)
// Strategy: bitwise-replicate numpy float32 reference:
//   t1 = np pairwise sum (128-block, 8-acc, fixed tree), dot = sequential-k FMA,
//   d = fl(fl(t1+t2) - 2*dot), argmin first-index tie-break, res -= emb[code].

#define GLD_G const __attribute__((address_space(1))) void*
#define GLD_L __attribute__((address_space(3))) void*

// ---------------- prep: transpose emb -> embT [256][1024] (pure copy) ----------------
__global__ __launch_bounds__(256) void prep_transpose(const float* __restrict__ emb,
                                                      float* __restrict__ embT) {
  __shared__ float tile[64][65];
  int tb = blockIdx.x;
  int c0 = (tb & 15) << 6;
  int d0 = (tb >> 4) << 6;
  int tx = threadIdx.x & 63;
  int ty = threadIdx.x >> 6;
#pragma unroll
  for (int i = 0; i < 16; ++i) {
    int c = (i << 2) + ty;
    tile[c][tx] = emb[(c0 + c) * 256 + d0 + tx];
  }
  __syncthreads();
#pragma unroll
  for (int i = 0; i < 16; ++i) {
    int d = (i << 2) + ty;
    embT[(d0 + d) * 1024 + c0 + tx] = tile[tx][d];
  }
}

// ---------------- prep: t2[c] = ||e_c||^2 via numpy pairwise order; zero loss ----------------
__global__ __launch_bounds__(256) void prep_t2(const float* __restrict__ emb,
                                               float* __restrict__ t2,
                                               float* __restrict__ out) {
#pragma clang fp contract(off)
  __shared__ float partials[16][16];
  int ci = threadIdx.x >> 4, part = threadIdx.x & 15;
  int bb = part >> 3, jj = part & 7;
  int c = (blockIdx.x << 4) + ci;
  const float* e = emb + c * 256 + bb * 128 + jj;
  float x = e[0];
  float acc = x * x;
  for (int i = 1; i < 16; ++i) { float y = e[i * 8]; acc = acc + y * y; }
  partials[ci][part] = acc;
  __syncthreads();
  if (part == 0) {
    const float* p = partials[ci];
    float B0 = ((p[0] + p[1]) + (p[2] + p[3])) + ((p[4] + p[5]) + (p[6] + p[7]));
    float B1 = ((p[8] + p[9]) + (p[10] + p[11])) + ((p[12] + p[13]) + (p[14] + p[15]));
    t2[c] = B0 + B1;
    if (c == 0) out[8388608] = 0.0f;
  }
}

// ---------------- main fused kernel: 4 faithful f32 GEMM+argmin rounds ----------------
// Block: 512 threads (8 waves), 32 rows x 1024 codes. Wave w owns cols [128w,128w+128).
__global__ __launch_bounds__(512, 4) void rq_main(const float* __restrict__ z,
                                                  const float* __restrict__ emb,
                                                  const float* __restrict__ embT,
                                                  const float* __restrict__ t2g,
                                                  float* __restrict__ out) {
  __shared__ float At[256 * 36];     // res transposed [k][r], row stride 36
  __shared__ float Bb[8 * 1024];     // embT K-chunk
  __shared__ float t2s[1024];
  __shared__ float t1part[32][16];   // pairwise partials per row
  __shared__ float t1s[32];
  __shared__ float redv[256];
  __shared__ int redi[256];
  __shared__ int codes_l[128];       // [32 rows][4 depths]
  __shared__ float lossAcc;

  const int tid = threadIdx.x;
  const int w = tid >> 6, l = tid & 63;
  const int n0 = blockIdx.x << 5;
  const int b = n0 >> 10, hw0 = n0 & 1023;
  const float* zbase = z + b * 262144 + hw0;

  // stage zf (transposed) into At
#pragma unroll
  for (int it = 0; it < 4; ++it) {
    int idx = it * 512 + tid;
    int k = idx >> 3, r4 = (idx & 7) << 2;
    *(float4*)(&At[k * 36 + r4]) = *(const float4*)(zbase + k * 1024 + r4);
  }
  // stage t2
  {
    int i = tid << 1;
    float2 v = *(const float2*)(t2g + i);
    t2s[i] = v.x; t2s[i + 1] = v.y;
  }
  if (tid == 0) lossAcc = 0.0f;
  __syncthreads();

  const int colbase = (w << 7) + (l << 1);
  const int rr_ = tid & 31, part_ = tid >> 5;
  const int kb0_ = (part_ >> 3) * 128 + (part_ & 7);  // pairwise start k for this thread

  for (int t = 0; t < 4; ++t) {
    // ---- t1 = numpy pairwise sum of res^2 per row (bitwise) ----
    {
#pragma clang fp contract(off)
      float x = At[kb0_ * 36 + rr_];
      float acc = x * x;
      for (int i = 1; i < 16; ++i) {
        float y = At[(kb0_ + i * 8) * 36 + rr_];
        acc = acc + y * y;
      }
      t1part[rr_][part_] = acc;
    }
    __syncthreads();
    if (tid < 32) {
#pragma clang fp contract(off)
      const float* p = t1part[tid];
      float B0 = ((p[0] + p[1]) + (p[2] + p[3])) + ((p[4] + p[5]) + (p[6] + p[7]));
      float B1 = ((p[8] + p[9]) + (p[10] + p[11])) + ((p[12] + p[13]) + (p[14] + p[15]));
      t1s[tid] = B0 + B1;
    }
    __syncthreads();
    if (t > 0 && tid == 0) {
      float s = 0.0f;
      for (int r = 0; r < 32; ++r) s += t1s[r];
      lossAcc += s;  // sum res_t^2, t = 1..3 here; final term added after loop
    }

    // ---- GEMM: dot[r][j] = sequential-k FMA chain (BLAS microkernel semantics) ----
    float acc0[32], acc1[32];
#pragma unroll
    for (int r = 0; r < 32; ++r) { acc0[r] = 0.0f; acc1[r] = 0.0f; }
    for (int kc = 0; kc < 32; ++kc) {
      const float* src = embT + (kc << 13);
#pragma unroll
      for (int it = 0; it < 4; ++it) {
        int base = it * 2048 + (w << 8);
        __builtin_amdgcn_global_load_lds((GLD_G)(src + base + (l << 2)),
                                         (GLD_L)(Bb + base), 16, 0, 0);
      }
      __syncthreads();
#pragma unroll
      for (int k = 0; k < 8; ++k) {
        const float* arow = &At[(kc * 8 + k) * 36];
        float2 bv = *(const float2*)(&Bb[(k << 10) + colbase]);
#pragma unroll
        for (int g = 0; g < 8; ++g) {
          float4 a4 = *(const float4*)(arow + (g << 2));
          acc0[g * 4 + 0] = __builtin_fmaf(a4.x, bv.x, acc0[g * 4 + 0]);
          acc1[g * 4 + 0] = __builtin_fmaf(a4.x, bv.y, acc1[g * 4 + 0]);
          acc0[g * 4 + 1] = __builtin_fmaf(a4.y, bv.x, acc0[g * 4 + 1]);
          acc1[g * 4 + 1] = __builtin_fmaf(a4.y, bv.y, acc1[g * 4 + 1]);
          acc0[g * 4 + 2] = __builtin_fmaf(a4.z, bv.x, acc0[g * 4 + 2]);
          acc1[g * 4 + 2] = __builtin_fmaf(a4.z, bv.y, acc1[g * 4 + 2]);
          acc0[g * 4 + 3] = __builtin_fmaf(a4.w, bv.x, acc0[g * 4 + 3]);
          acc1[g * 4 + 3] = __builtin_fmaf(a4.w, bv.y, acc1[g * 4 + 3]);
        }
      }
      __syncthreads();
    }

    // ---- d = fl(fl(t1+t2) - 2*dot); argmin with first-index tie-break ----
#pragma unroll
    for (int r = 0; r < 32; ++r) {
      float t1r = t1s[r];
      float ab0 = t1r + t2s[colbase];
      float ab1 = t1r + t2s[colbase + 1];
      float d0 = ab0 - 2.0f * acc0[r];  // 2*dot exact; single-rounded subtract
      float d1 = ab1 - 2.0f * acc1[r];
      float v = d0; int ci = colbase;
      if (d1 < v) { v = d1; ci = colbase + 1; }
#pragma unroll
      for (int m = 1; m < 64; m <<= 1) {
        float ov = __shfl_xor(v, m, 64);
        int oi = __shfl_xor(ci, m, 64);
        bool better = (ov < v) || (ov == v && oi < ci);
        v = better ? ov : v;
        ci = better ? oi : ci;
      }
      if (l == 0) { redv[(r << 3) + w] = v; redi[(r << 3) + w] = ci; }
    }
    __syncthreads();
    if (tid < 32) {
      int r = tid;
      float v = redv[r << 3];
      int ci = redi[r << 3];
#pragma unroll
      for (int w2 = 1; w2 < 8; ++w2) {
        float ov = redv[(r << 3) + w2];
        int oi = redi[(r << 3) + w2];
        bool better = (ov < v) || (ov == v && oi < ci);
        v = better ? ov : v;
        ci = better ? oi : ci;
      }
      codes_l[(r << 2) + t] = ci;
    }
    __syncthreads();

    // ---- res -= emb[code]  (elementwise f32, bitwise) ----
    {
      int c = codes_l[(rr_ << 2) + t];
      const float* er = emb + (c << 8) + (part_ << 4);
      int kb = part_ << 4;
      float4 e0 = *(const float4*)(er);
      float4 e1 = *(const float4*)(er + 4);
      float4 e2 = *(const float4*)(er + 8);
      float4 e3 = *(const float4*)(er + 12);
      At[(kb + 0) * 36 + rr_] -= e0.x;  At[(kb + 1) * 36 + rr_] -= e0.y;
      At[(kb + 2) * 36 + rr_] -= e0.z;  At[(kb + 3) * 36 + rr_] -= e0.w;
      At[(kb + 4) * 36 + rr_] -= e1.x;  At[(kb + 5) * 36 + rr_] -= e1.y;
      At[(kb + 6) * 36 + rr_] -= e1.z;  At[(kb + 7) * 36 + rr_] -= e1.w;
      At[(kb + 8) * 36 + rr_] -= e2.x;  At[(kb + 9) * 36 + rr_] -= e2.y;
      At[(kb + 10) * 36 + rr_] -= e2.z; At[(kb + 11) * 36 + rr_] -= e2.w;
      At[(kb + 12) * 36 + rr_] -= e3.x; At[(kb + 13) * 36 + rr_] -= e3.y;
      At[(kb + 14) * 36 + rr_] -= e3.z; At[(kb + 15) * 36 + rr_] -= e3.w;
    }
    __syncthreads();
  }  // depth loop

  // ---- final loss term: sumsq(res_4) ----
  {
#pragma clang fp contract(off)
    float x = At[kb0_ * 36 + rr_];
    float acc = x * x;
    for (int i = 1; i < 16; ++i) {
      float y = At[(kb0_ + i * 8) * 36 + rr_];
      acc = acc + y * y;
    }
    t1part[rr_][part_] = acc;
  }
  __syncthreads();
  if (tid < 32) {
#pragma clang fp contract(off)
    const float* p = t1part[tid];
    float B0 = ((p[0] + p[1]) + (p[2] + p[3])) + ((p[4] + p[5]) + (p[6] + p[7]));
    float B1 = ((p[8] + p[9]) + (p[10] + p[11])) + ((p[12] + p[13]) + (p[14] + p[15]));
    t1s[tid] = B0 + B1;
  }
  __syncthreads();
  if (tid == 0) {
    float s = 0.0f;
    for (int r = 0; r < 32; ++r) s += t1s[r];
    float total = lossAcc + s;  // sum_{t=1..4} sum res_t^2  (~= sum (agg_t - zf)^2)
    atomicAdd(out + 8388608, total * (11.0f / 8388608.0f));
  }
  __syncthreads();

  // ---- z_q = agg chain (np z_q = agg4 +- 1e-7, threshold 20.48) ----
  // wave w -> rows 4w..4w+3, lane l -> dims 4l..4l+3
  const int r0 = w << 2;
  float agg[4][4];
#pragma unroll
  for (int rr = 0; rr < 4; ++rr)
#pragma unroll
    for (int jj = 0; jj < 4; ++jj) agg[rr][jj] = 0.0f;
  for (int t = 0; t < 4; ++t) {
#pragma unroll
    for (int rr = 0; rr < 4; ++rr) {
      int c = codes_l[((r0 + rr) << 2) + t];
      float4 e4 = *(const float4*)(emb + (c << 8) + (l << 2));
      agg[rr][0] += e4.x; agg[rr][1] += e4.y; agg[rr][2] += e4.z; agg[rr][3] += e4.w;
    }
  }
#pragma unroll
  for (int rr = 0; rr < 4; ++rr)
#pragma unroll
    for (int jj = 0; jj < 4; ++jj)
      At[((l << 2) + jj) * 36 + r0 + rr] = agg[rr][jj];
  __syncthreads();
  float* zqbase = out + b * 262144 + hw0;
#pragma unroll
  for (int it = 0; it < 16; ++it) {
    int d = (it << 4) + (tid >> 5);
    int r = tid & 31;
    zqbase[d * 1024 + r] = At[d * 36 + r];
  }
  // codes as f32
  if (tid < 128) {
    int n = tid >> 2, tt = tid & 3;
    out[8388609 + ((n0 + n) << 2) + tt] = (float)codes_l[(n << 2) + tt];
  }
}

extern "C" void kernel_launch(void* const* d_in, const int* in_sizes, int n_in,
                              void* d_out, int out_size, void* d_ws, size_t ws_size,
                              hipStream_t stream) {
  const float* z = (const float*)d_in[0];
  const float* emb = (const float*)d_in[1];
  float* out = (float*)d_out;
  float* ws = (float*)d_ws;
  float* embT = ws;            // 262144 f32
  float* t2 = ws + 262144;     // 1024 f32

  hipLaunchKernelGGL(prep_transpose, dim3(64), dim3(256), 0, stream, emb, embT);
  hipLaunchKernelGGL(prep_t2, dim3(64), dim3(256), 0, stream, emb, t2, out);
  hipLaunchKernelGGL(rq_main, dim3(1024), dim3(512), 0, stream, z, emb, embT, t2, out);
}